// Round 1
// baseline (3410.606 us; speedup 1.0000x reference)
//
#include <hip/hip_runtime.h>

// ---------------------------------------------------------------------------
// MOF_Net: DGCN(graph2) -> e_t ; MOLGCN(graph1) -> h ; global add pool /2
// Sizes: N1=20000, E1=640000, N2=640000(==E1), E2=1280000
// d_x1=32, d_x2=32, d_e2=16, d_h=64, d_et=32, d_out=32, G=64
// ---------------------------------------------------------------------------

#define NUM_GRAPHS 64

// Stage 1: per edge of graph2, msg = MLP2([x2[src](32), edge_attr2(16)]) ; atomic add to e_t[dst]
__global__ __launch_bounds__(256) void k_edge2(
    const float* __restrict__ x2, const int* __restrict__ ei2,
    const float* __restrict__ ea2,
    const float* __restrict__ W2a, const float* __restrict__ b2a,
    const float* __restrict__ W2b, const float* __restrict__ b2b,
    float* __restrict__ e_t, int E2)
{
    __shared__ float sWa[48 * 64];
    __shared__ float sWb[64 * 32];
    __shared__ float sba[64];
    __shared__ float sbb[32];
    const int t = threadIdx.x;
    for (int i = t; i < 48 * 64; i += 256) sWa[i] = W2a[i];
    for (int i = t; i < 64 * 32; i += 256) sWb[i] = W2b[i];
    if (t < 64) sba[t] = b2a[t];
    if (t < 32) sbb[t] = b2b[t];
    __syncthreads();

    const int e = blockIdx.x * 256 + t;
    if (e >= E2) return;

    const int s = ei2[e];
    const int d = ei2[E2 + e];

    float in[48];
    {
        const float4* xs = (const float4*)(x2 + (size_t)s * 32);
        #pragma unroll
        for (int q = 0; q < 8; ++q) {
            float4 v = xs[q];
            in[4 * q + 0] = v.x; in[4 * q + 1] = v.y;
            in[4 * q + 2] = v.z; in[4 * q + 3] = v.w;
        }
        const float4* es = (const float4*)(ea2 + (size_t)e * 16);
        #pragma unroll
        for (int q = 0; q < 4; ++q) {
            float4 v = es[q];
            in[32 + 4 * q + 0] = v.x; in[32 + 4 * q + 1] = v.y;
            in[32 + 4 * q + 2] = v.z; in[32 + 4 * q + 3] = v.w;
        }
    }

    float out[32];
    #pragma unroll
    for (int i = 0; i < 32; ++i) out[i] = sbb[i];

    #pragma unroll 4
    for (int j = 0; j < 64; ++j) {
        float h = sba[j];
        #pragma unroll
        for (int k = 0; k < 48; ++k) h += in[k] * sWa[k * 64 + j];
        h = fmaxf(h, 0.0f);
        #pragma unroll
        for (int i = 0; i < 32; ++i) out[i] += h * sWb[j * 32 + i];
    }

    float* dst = e_t + (size_t)d * 32;
    #pragma unroll
    for (int i = 0; i < 32; ++i) atomicAdd(dst + i, out[i]);
}

// Stage 2: per edge of graph1, msg = MLP1([x1[src](32), e_t[e](32)]) ; atomic add to h[dst]
__global__ __launch_bounds__(256) void k_edge1(
    const float* __restrict__ x1, const int* __restrict__ ei1,
    const float* __restrict__ e_t,
    const float* __restrict__ W1a, const float* __restrict__ b1a,
    const float* __restrict__ W1b, const float* __restrict__ b1b,
    float* __restrict__ h_out, int E1)
{
    __shared__ float sWa[64 * 64];
    __shared__ float sWb[64 * 32];
    __shared__ float sba[64];
    __shared__ float sbb[32];
    const int t = threadIdx.x;
    for (int i = t; i < 64 * 64; i += 256) sWa[i] = W1a[i];
    for (int i = t; i < 64 * 32; i += 256) sWb[i] = W1b[i];
    if (t < 64) sba[t] = b1a[t];
    if (t < 32) sbb[t] = b1b[t];
    __syncthreads();

    const int e = blockIdx.x * 256 + t;
    if (e >= E1) return;

    const int s = ei1[e];
    const int d = ei1[E1 + e];

    float in[64];
    {
        const float4* xs = (const float4*)(x1 + (size_t)s * 32);
        #pragma unroll
        for (int q = 0; q < 8; ++q) {
            float4 v = xs[q];
            in[4 * q + 0] = v.x; in[4 * q + 1] = v.y;
            in[4 * q + 2] = v.z; in[4 * q + 3] = v.w;
        }
        const float4* es = (const float4*)(e_t + (size_t)e * 32);
        #pragma unroll
        for (int q = 0; q < 8; ++q) {
            float4 v = es[q];
            in[32 + 4 * q + 0] = v.x; in[32 + 4 * q + 1] = v.y;
            in[32 + 4 * q + 2] = v.z; in[32 + 4 * q + 3] = v.w;
        }
    }

    float out[32];
    #pragma unroll
    for (int i = 0; i < 32; ++i) out[i] = sbb[i];

    #pragma unroll 4
    for (int j = 0; j < 64; ++j) {
        float h = sba[j];
        #pragma unroll
        for (int k = 0; k < 64; ++k) h += in[k] * sWa[k * 64 + j];
        h = fmaxf(h, 0.0f);
        #pragma unroll
        for (int i = 0; i < 32; ++i) out[i] += h * sWb[j * 32 + i];
    }

    float* dst = h_out + (size_t)d * 32;
    #pragma unroll
    for (int i = 0; i < 32; ++i) atomicAdd(dst + i, out[i]);
}

// Stage 3: pooled[batch[n]] += h[n] * 0.5
__global__ __launch_bounds__(256) void k_pool(
    const float* __restrict__ h, const int* __restrict__ batch,
    float* __restrict__ out, int N1)
{
    const int idx = blockIdx.x * 256 + threadIdx.x;
    if (idx >= N1 * 32) return;
    const int n = idx >> 5;
    const int c = idx & 31;
    atomicAdd(out + (size_t)batch[n] * 32 + c, h[idx] * 0.5f);
}

extern "C" void kernel_launch(void* const* d_in, const int* in_sizes, int n_in,
                              void* d_out, int out_size, void* d_ws, size_t ws_size,
                              hipStream_t stream) {
    const float* x1   = (const float*)d_in[0];
    const float* x2   = (const float*)d_in[1];
    const int*   ei1  = (const int*)d_in[2];
    const int*   ei2  = (const int*)d_in[3];
    const int*   xb   = (const int*)d_in[4];
    const float* ea2  = (const float*)d_in[5];
    const float* W2a  = (const float*)d_in[6];
    const float* b2a  = (const float*)d_in[7];
    const float* W2b  = (const float*)d_in[8];
    const float* b2b  = (const float*)d_in[9];
    const float* W1a  = (const float*)d_in[10];
    const float* b1a  = (const float*)d_in[11];
    const float* W1b  = (const float*)d_in[12];
    const float* b1b  = (const float*)d_in[13];

    const int N1 = in_sizes[0] / 32;   // 20000
    const int E1 = in_sizes[2] / 2;    // 640000
    const int E2 = in_sizes[3] / 2;    // 1280000
    const int N2 = in_sizes[1] / 32;   // 640000 (== E1, line graph)

    // workspace layout
    float* e_t = (float*)d_ws;                           // N2*32 floats
    float* h   = e_t + (size_t)N2 * 32;                  // N1*32 floats

    hipMemsetAsync(e_t, 0, (size_t)N2 * 32 * sizeof(float), stream);
    hipMemsetAsync(h,   0, (size_t)N1 * 32 * sizeof(float), stream);
    hipMemsetAsync(d_out, 0, (size_t)out_size * sizeof(float), stream);

    k_edge2<<<(E2 + 255) / 256, 256, 0, stream>>>(x2, ei2, ea2, W2a, b2a, W2b, b2b, e_t, E2);
    k_edge1<<<(E1 + 255) / 256, 256, 0, stream>>>(x1, ei1, e_t, W1a, b1a, W1b, b1b, h, E1);
    k_pool<<<(N1 * 32 + 255) / 256, 256, 0, stream>>>(h, xb, (float*)d_out, N1);
}

// Round 2
// 843.181 us; speedup vs baseline: 4.0449x; 4.0449x over previous
//
#include <hip/hip_runtime.h>
#include <hip/hip_bf16.h>

// ---------------------------------------------------------------------------
// MOF_Net: DGCN(graph2) -> e_t ; MOLGCN(graph1) -> h ; global add pool /2
// N1=20000, E1=640000, N2=640000(==E1), E2=1280000
// Strategy: counting-sort edges by dst, then fused MLP + LDS segmented
// reduction with direct stores (atomic-free except block-boundary partials).
// ---------------------------------------------------------------------------

#define NUM_GRAPHS 64

__device__ __forceinline__ unsigned short f2bf(float x) {
    __hip_bfloat16 b = __float2bfloat16(x);
    return *(unsigned short*)&b;
}
__device__ __forceinline__ float bf2f(unsigned int u16) {
    unsigned short us = (unsigned short)u16;
    __hip_bfloat16 b = *(__hip_bfloat16*)&us;
    return __bfloat162float(b);
}
__device__ __forceinline__ unsigned int pack2(float lo, float hi) {
    return (unsigned int)f2bf(lo) | ((unsigned int)f2bf(hi) << 16);
}

// ---------------- counting sort: histogram / scan / scatter ----------------

__global__ __launch_bounds__(256) void k_hist(const int* __restrict__ dst,
                                              int* __restrict__ cnt, int E) {
    int e = blockIdx.x * 256 + threadIdx.x;
    if (e < E) atomicAdd(&cnt[dst[e]], 1);
}

#define SCAN_PT 8
#define SCAN_EPB 2048  // 256 threads * 8

__global__ __launch_bounds__(256) void k_scan_partial(int* __restrict__ data,
                                                      int* __restrict__ aux, int N) {
    const int tid = threadIdx.x;
    const int base = blockIdx.x * SCAN_EPB + tid * SCAN_PT;
    int v[SCAN_PT];
    int tot = 0;
    #pragma unroll
    for (int i = 0; i < SCAN_PT; ++i) {
        int idx = base + i;
        v[i] = (idx < N) ? data[idx] : 0;
        tot += v[i];
    }
    const int lane = tid & 63, wid = tid >> 6;
    int inc = tot;
    #pragma unroll
    for (int off = 1; off < 64; off <<= 1) {
        int n = __shfl_up(inc, off, 64);
        if (lane >= off) inc += n;
    }
    __shared__ int wsum[4];
    if (lane == 63) wsum[wid] = inc;
    __syncthreads();
    int wpre = 0;
    for (int w = 0; w < wid; ++w) wpre += wsum[w];
    int run = wpre + inc - tot;  // exclusive prefix for this thread
    #pragma unroll
    for (int i = 0; i < SCAN_PT; ++i) {
        int idx = base + i;
        if (idx < N) data[idx] = run;
        run += v[i];
    }
    if (tid == 255) aux[blockIdx.x] = wpre + inc;  // block total
}

__global__ __launch_bounds__(512) void k_scan_aux(int* __restrict__ aux, int G) {
    const int tid = threadIdx.x;
    int v = (tid < G) ? aux[tid] : 0;
    const int lane = tid & 63, wid = tid >> 6;
    int inc = v;
    #pragma unroll
    for (int off = 1; off < 64; off <<= 1) {
        int n = __shfl_up(inc, off, 64);
        if (lane >= off) inc += n;
    }
    __shared__ int wsum[8];
    if (lane == 63) wsum[wid] = inc;
    __syncthreads();
    int wpre = 0;
    for (int w = 0; w < wid; ++w) wpre += wsum[w];
    if (tid < G) aux[tid] = wpre + inc - v;
}

__global__ __launch_bounds__(256) void k_scan_add(int* __restrict__ data,
                                                  const int* __restrict__ aux, int N) {
    const int add = aux[blockIdx.x];
    const int base = blockIdx.x * SCAN_EPB + threadIdx.x * SCAN_PT;
    #pragma unroll
    for (int i = 0; i < SCAN_PT; ++i) {
        int idx = base + i;
        if (idx < N) data[idx] += add;
    }
}

__global__ __launch_bounds__(256) void k_scatter(const int* __restrict__ dst,
                                                 int* __restrict__ cursor,
                                                 int* __restrict__ order, int E) {
    int e = blockIdx.x * 256 + threadIdx.x;
    if (e < E) {
        int pos = atomicAdd(&cursor[dst[e]], 1);
        order[pos] = e;
    }
}

// ---------------- stage 1: per-edge MLP2 + segmented reduce -> e_t (bf16) --

__global__ __launch_bounds__(256) void k_msg2_agg(
    const float* __restrict__ x2, const float* __restrict__ ea2,
    const int* __restrict__ ei2, const int* __restrict__ order,
    const float* __restrict__ Wa, const float* __restrict__ ba,
    const float* __restrict__ Wb, const float* __restrict__ bb,
    unsigned int* __restrict__ e_t, int E)
{
    __shared__ float sWa[48 * 64];
    __shared__ float sWb[64 * 32];
    __shared__ float sba[64], sbb[32];
    __shared__ float smsg[256][33];  // +1 pad: spread leader reads across banks
    __shared__ int sdst[257];
    const int tid = threadIdx.x;
    for (int i = tid; i < 48 * 64; i += 256) sWa[i] = Wa[i];
    for (int i = tid; i < 64 * 32; i += 256) sWb[i] = Wb[i];
    if (tid < 64) sba[tid] = ba[tid];
    if (tid < 32) sbb[tid] = bb[tid];

    const int base = blockIdx.x * 256, p = base + tid;
    int e = 0, s = 0, d = -1;
    if (p < E) { e = order[p]; s = ei2[e]; d = ei2[E + e]; }
    sdst[tid] = d;
    int dprev = -1;
    if (tid == 0) {
        if (base > 0) { int ep = order[base - 1]; dprev = ei2[E + ep]; }
        int dn = -1;
        if (base + 256 < E) { int en = order[base + 256]; dn = ei2[E + en]; }
        sdst[256] = dn;
    }
    __syncthreads();

    if (p < E) {
        float in[48];
        const float4* xs = (const float4*)(x2 + (size_t)s * 32);
        #pragma unroll
        for (int q = 0; q < 8; ++q) {
            float4 v = xs[q];
            in[4 * q + 0] = v.x; in[4 * q + 1] = v.y;
            in[4 * q + 2] = v.z; in[4 * q + 3] = v.w;
        }
        const float4* es = (const float4*)(ea2 + (size_t)e * 16);
        #pragma unroll
        for (int q = 0; q < 4; ++q) {
            float4 v = es[q];
            in[32 + 4 * q + 0] = v.x; in[32 + 4 * q + 1] = v.y;
            in[32 + 4 * q + 2] = v.z; in[32 + 4 * q + 3] = v.w;
        }
        float out[32];
        #pragma unroll
        for (int i = 0; i < 32; ++i) out[i] = sbb[i];
        #pragma unroll 4
        for (int j = 0; j < 64; ++j) {
            float hh = sba[j];
            #pragma unroll
            for (int k = 0; k < 48; ++k) hh = fmaf(in[k], sWa[k * 64 + j], hh);
            hh = fmaxf(hh, 0.0f);
            #pragma unroll
            for (int i = 0; i < 32; ++i) out[i] = fmaf(hh, sWb[j * 32 + i], out[i]);
        }
        #pragma unroll
        for (int c = 0; c < 32; ++c) smsg[tid][c] = out[c];
    }
    __syncthreads();

    const bool leader = (p < E) && (tid == 0 || sdst[tid - 1] != d);
    if (leader) {
        int qend = tid;
        while (qend + 1 < 256 && sdst[qend + 1] == d) ++qend;
        float acc[32];
        #pragma unroll
        for (int c = 0; c < 32; ++c) acc[c] = smsg[tid][c];
        for (int q = tid + 1; q <= qend; ++q) {
            #pragma unroll
            for (int c = 0; c < 32; ++c) acc[c] += smsg[q][c];
        }
        const bool gs = (tid > 0) || (base == 0) || (dprev != d);
        const bool ge = (qend < 255) || (sdst[256] != d);
        unsigned int* row = e_t + (size_t)d * 16;
        if (gs && ge) {
            // full segment: plain store
            #pragma unroll
            for (int c = 0; c < 16; ++c) row[c] = pack2(acc[2 * c], acc[2 * c + 1]);
        } else {
            // split segment: CAS-add bf16x2 (rare: <=2 runs per block)
            for (int c = 0; c < 16; ++c) {
                unsigned int* addr = row + c;
                unsigned int old = *addr;
                while (true) {
                    float lo = bf2f(old & 0xffffu) + acc[2 * c];
                    float hi = bf2f(old >> 16) + acc[2 * c + 1];
                    unsigned int nv = pack2(lo, hi);
                    unsigned int prev = atomicCAS(addr, old, nv);
                    if (prev == old) break;
                    old = prev;
                }
            }
        }
    }
}

// ---------------- stage 2: per-edge MLP1 + segmented reduce -> h (f32) -----

__global__ __launch_bounds__(256) void k_msg1_agg(
    const float* __restrict__ x1, const unsigned int* __restrict__ e_t,
    const int* __restrict__ ei1, const int* __restrict__ order,
    const float* __restrict__ Wa, const float* __restrict__ ba,
    const float* __restrict__ Wb, const float* __restrict__ bb,
    float* __restrict__ h, int E)
{
    __shared__ float sWa[64 * 64];
    __shared__ float sWb[64 * 32];
    __shared__ float sba[64], sbb[32];
    __shared__ float smsg[256][33];
    __shared__ int sdst[257];
    const int tid = threadIdx.x;
    for (int i = tid; i < 64 * 64; i += 256) sWa[i] = Wa[i];
    for (int i = tid; i < 64 * 32; i += 256) sWb[i] = Wb[i];
    if (tid < 64) sba[tid] = ba[tid];
    if (tid < 32) sbb[tid] = bb[tid];

    const int base = blockIdx.x * 256, p = base + tid;
    int e = 0, s = 0, d = -1;
    if (p < E) { e = order[p]; s = ei1[e]; d = ei1[E + e]; }
    sdst[tid] = d;
    int dprev = -1;
    if (tid == 0) {
        if (base > 0) { int ep = order[base - 1]; dprev = ei1[E + ep]; }
        int dn = -1;
        if (base + 256 < E) { int en = order[base + 256]; dn = ei1[E + en]; }
        sdst[256] = dn;
    }
    __syncthreads();

    if (p < E) {
        float in[64];
        const float4* xs = (const float4*)(x1 + (size_t)s * 32);
        #pragma unroll
        for (int q = 0; q < 8; ++q) {
            float4 v = xs[q];
            in[4 * q + 0] = v.x; in[4 * q + 1] = v.y;
            in[4 * q + 2] = v.z; in[4 * q + 3] = v.w;
        }
        const unsigned int* er = e_t + (size_t)e * 16;
        #pragma unroll
        for (int c = 0; c < 16; ++c) {
            unsigned int u = er[c];
            in[32 + 2 * c] = bf2f(u & 0xffffu);
            in[32 + 2 * c + 1] = bf2f(u >> 16);
        }
        float out[32];
        #pragma unroll
        for (int i = 0; i < 32; ++i) out[i] = sbb[i];
        #pragma unroll 4
        for (int j = 0; j < 64; ++j) {
            float hh = sba[j];
            #pragma unroll
            for (int k = 0; k < 64; ++k) hh = fmaf(in[k], sWa[k * 64 + j], hh);
            hh = fmaxf(hh, 0.0f);
            #pragma unroll
            for (int i = 0; i < 32; ++i) out[i] = fmaf(hh, sWb[j * 32 + i], out[i]);
        }
        #pragma unroll
        for (int c = 0; c < 32; ++c) smsg[tid][c] = out[c];
    }
    __syncthreads();

    const bool leader = (p < E) && (tid == 0 || sdst[tid - 1] != d);
    if (leader) {
        int qend = tid;
        while (qend + 1 < 256 && sdst[qend + 1] == d) ++qend;
        float acc[32];
        #pragma unroll
        for (int c = 0; c < 32; ++c) acc[c] = smsg[tid][c];
        for (int q = tid + 1; q <= qend; ++q) {
            #pragma unroll
            for (int c = 0; c < 32; ++c) acc[c] += smsg[q][c];
        }
        const bool gs = (tid > 0) || (base == 0) || (dprev != d);
        const bool ge = (qend < 255) || (sdst[256] != d);
        float* row = h + (size_t)d * 32;
        if (gs && ge) {
            #pragma unroll
            for (int q = 0; q < 8; ++q) {
                float4 v = make_float4(acc[4 * q], acc[4 * q + 1], acc[4 * q + 2], acc[4 * q + 3]);
                ((float4*)row)[q] = v;
            }
        } else {
            for (int c = 0; c < 32; ++c) atomicAdd(row + c, acc[c]);
        }
    }
}

// ---------------- stage 3: pool per graph (batch is sorted) ----------------

__device__ __forceinline__ int lower_bound_i(const int* a, int n, int key) {
    int lo = 0, hi = n;
    while (lo < hi) {
        int mid = (lo + hi) >> 1;
        if (a[mid] < key) lo = mid + 1; else hi = mid;
    }
    return lo;
}

__global__ __launch_bounds__(256) void k_pool(const float* __restrict__ h,
                                              const int* __restrict__ batch,
                                              float* __restrict__ out, int N1) {
    const int g = blockIdx.x;
    const int lo = lower_bound_i(batch, N1, g);
    const int hi = lower_bound_i(batch, N1, g + 1);
    const int tid = threadIdx.x;
    const int c = tid & 31, rg = tid >> 5;  // 8 row-groups x 32 channels
    float acc = 0.0f;
    for (int n = lo + rg; n < hi; n += 8) acc += h[(size_t)n * 32 + c];
    __shared__ float red[256];
    red[tid] = acc;
    __syncthreads();
    for (int off = 128; off >= 32; off >>= 1) {
        if (tid < off) red[tid] += red[tid + off];
        __syncthreads();
    }
    if (tid < 32) out[g * 32 + tid] = red[tid] * 0.5f;
}

// ---------------------------------------------------------------------------

extern "C" void kernel_launch(void* const* d_in, const int* in_sizes, int n_in,
                              void* d_out, int out_size, void* d_ws, size_t ws_size,
                              hipStream_t stream) {
    const float* x1  = (const float*)d_in[0];
    const float* x2  = (const float*)d_in[1];
    const int*   ei1 = (const int*)d_in[2];
    const int*   ei2 = (const int*)d_in[3];
    const int*   xb  = (const int*)d_in[4];
    const float* ea2 = (const float*)d_in[5];
    const float* W2a = (const float*)d_in[6];
    const float* b2a = (const float*)d_in[7];
    const float* W2b = (const float*)d_in[8];
    const float* b2b = (const float*)d_in[9];
    const float* W1a = (const float*)d_in[10];
    const float* b1a = (const float*)d_in[11];
    const float* W1b = (const float*)d_in[12];
    const float* b1b = (const float*)d_in[13];

    const int N1 = in_sizes[0] / 32;   // 20000
    const int E1 = in_sizes[2] / 2;    // 640000
    const int E2 = in_sizes[3] / 2;    // 1280000
    const int N2 = in_sizes[1] / 32;   // 640000 (== E1)

    // workspace layout (all sizes multiple of 16B)
    char* w = (char*)d_ws;
    unsigned int* e_t = (unsigned int*)w;            w += (size_t)N2 * 32 * 2;  // bf16 [N2,32]
    int* cursor2      = (int*)w;                     w += (size_t)N2 * 4;
    int* order2       = (int*)w;                     w += (size_t)E2 * 4;
    int* aux          = (int*)w;                     w += 512 * 4;
    float* h          = (float*)w;                   w += (size_t)N1 * 32 * 4;
    int* cursor1      = (int*)w;                     w += (size_t)N1 * 4;
    int* order1       = (int*)w;                     /* total ~54 MB */

    const int G2 = (N2 + SCAN_EPB - 1) / SCAN_EPB;  // 313
    const int G1 = (N1 + SCAN_EPB - 1) / SCAN_EPB;  // 10

    // ---- graph 2: counting sort by dst ----
    hipMemsetAsync(cursor2, 0, (size_t)N2 * 4, stream);
    hipMemsetAsync(e_t, 0, (size_t)N2 * 32 * 2, stream);
    k_hist<<<(E2 + 255) / 256, 256, 0, stream>>>(ei2 + E2, cursor2, E2);
    k_scan_partial<<<G2, 256, 0, stream>>>(cursor2, aux, N2);
    k_scan_aux<<<1, 512, 0, stream>>>(aux, G2);
    k_scan_add<<<G2, 256, 0, stream>>>(cursor2, aux, N2);
    k_scatter<<<(E2 + 255) / 256, 256, 0, stream>>>(ei2 + E2, cursor2, order2, E2);

    // ---- stage 1: fused MLP2 + segment sum -> e_t ----
    k_msg2_agg<<<(E2 + 255) / 256, 256, 0, stream>>>(
        x2, ea2, ei2, order2, W2a, b2a, W2b, b2b, e_t, E2);

    // ---- graph 1: counting sort by dst ----
    hipMemsetAsync(cursor1, 0, (size_t)N1 * 4, stream);
    hipMemsetAsync(h, 0, (size_t)N1 * 32 * 4, stream);
    k_hist<<<(E1 + 255) / 256, 256, 0, stream>>>(ei1 + E1, cursor1, E1);
    k_scan_partial<<<G1, 256, 0, stream>>>(cursor1, aux, N1);
    k_scan_aux<<<1, 512, 0, stream>>>(aux, G1);
    k_scan_add<<<G1, 256, 0, stream>>>(cursor1, aux, N1);
    k_scatter<<<(E1 + 255) / 256, 256, 0, stream>>>(ei1 + E1, cursor1, order1, E1);

    // ---- stage 2: fused MLP1 + segment sum -> h ----
    k_msg1_agg<<<(E1 + 255) / 256, 256, 0, stream>>>(
        x1, e_t, ei1, order1, W1a, b1a, W1b, b1b, h, E1);

    // ---- stage 3: pool ----
    k_pool<<<NUM_GRAPHS, 256, 0, stream>>>(h, xb, (float*)d_out, N1);
}

// Round 3
// 577.453 us; speedup vs baseline: 5.9063x; 1.4602x over previous
//
#include <hip/hip_runtime.h>
#include <hip/hip_bf16.h>

// ---------------------------------------------------------------------------
// MOF_Net: DGCN(graph2) -> e_t ; MOLGCN(graph1) -> h ; global add pool /2
// N1=20000, E1=640000, N2=640000(==E1), E2=1280000
// Round 2: MLPs via bf16 MFMA (16x16x32), LDS-staged swizzled inputs,
// counting-sort + segmented reduce with direct stores kept from round 1.
// ---------------------------------------------------------------------------

#define NUM_GRAPHS 64

typedef __attribute__((ext_vector_type(8))) short bf16x8;
typedef __attribute__((ext_vector_type(4))) float f32x4;

__device__ __forceinline__ unsigned short f2bf(float x) {
    __hip_bfloat16 b = __float2bfloat16(x);
    return *(unsigned short*)&b;
}
__device__ __forceinline__ float bf2f(unsigned int u16) {
    unsigned short us = (unsigned short)u16;
    __hip_bfloat16 b = *(__hip_bfloat16*)&us;
    return __bfloat162float(b);
}
__device__ __forceinline__ unsigned int pack2(float lo, float hi) {
    return (unsigned int)f2bf(lo) | ((unsigned int)f2bf(hi) << 16);
}
// swizzled byte address within a [row][64 bf16] tile (rowbytes=128):
// XOR bits 4-6 with row&7 -> A-frag ds_read_b128 is 2-way (free) not 16-way
__device__ __forceinline__ int swz(int row, int kb) {
    return row * 128 + (kb ^ ((row & 7) << 4));
}

// ---------------- counting sort: histogram / scan / scatter ----------------

__global__ __launch_bounds__(256) void k_hist(const int* __restrict__ dst,
                                              int* __restrict__ cnt, int E) {
    int e = blockIdx.x * 256 + threadIdx.x;
    if (e < E) atomicAdd(&cnt[dst[e]], 1);
}

#define SCAN_PT 8
#define SCAN_EPB 2048  // 256 threads * 8

__global__ __launch_bounds__(256) void k_scan_partial(int* __restrict__ data,
                                                      int* __restrict__ aux, int N) {
    const int tid = threadIdx.x;
    const int base = blockIdx.x * SCAN_EPB + tid * SCAN_PT;
    int v[SCAN_PT];
    int tot = 0;
    #pragma unroll
    for (int i = 0; i < SCAN_PT; ++i) {
        int idx = base + i;
        v[i] = (idx < N) ? data[idx] : 0;
        tot += v[i];
    }
    const int lane = tid & 63, wid = tid >> 6;
    int inc = tot;
    #pragma unroll
    for (int off = 1; off < 64; off <<= 1) {
        int n = __shfl_up(inc, off, 64);
        if (lane >= off) inc += n;
    }
    __shared__ int wsum[4];
    if (lane == 63) wsum[wid] = inc;
    __syncthreads();
    int wpre = 0;
    for (int w = 0; w < wid; ++w) wpre += wsum[w];
    int run = wpre + inc - tot;  // exclusive prefix for this thread
    #pragma unroll
    for (int i = 0; i < SCAN_PT; ++i) {
        int idx = base + i;
        if (idx < N) data[idx] = run;
        run += v[i];
    }
    if (tid == 255) aux[blockIdx.x] = wpre + inc;  // block total
}

__global__ __launch_bounds__(512) void k_scan_aux(int* __restrict__ aux, int G) {
    const int tid = threadIdx.x;
    int v = (tid < G) ? aux[tid] : 0;
    const int lane = tid & 63, wid = tid >> 6;
    int inc = v;
    #pragma unroll
    for (int off = 1; off < 64; off <<= 1) {
        int n = __shfl_up(inc, off, 64);
        if (lane >= off) inc += n;
    }
    __shared__ int wsum[8];
    if (lane == 63) wsum[wid] = inc;
    __syncthreads();
    int wpre = 0;
    for (int w = 0; w < wid; ++w) wpre += wsum[w];
    if (tid < G) aux[tid] = wpre + inc - v;
}

__global__ __launch_bounds__(256) void k_scan_add(int* __restrict__ data,
                                                  const int* __restrict__ aux, int N) {
    const int add = aux[blockIdx.x];
    const int base = blockIdx.x * SCAN_EPB + threadIdx.x * SCAN_PT;
    #pragma unroll
    for (int i = 0; i < SCAN_PT; ++i) {
        int idx = base + i;
        if (idx < N) data[idx] += add;
    }
}

__global__ __launch_bounds__(256) void k_scatter(const int* __restrict__ dst,
                                                 int* __restrict__ cursor,
                                                 int* __restrict__ order, int E) {
    int e = blockIdx.x * 256 + threadIdx.x;
    if (e < E) {
        int pos = atomicAdd(&cursor[dst[e]], 1);
        order[pos] = e;
    }
}

// ---------------- stage 1: MFMA MLP2 + segmented reduce -> e_t (bf16) -----

__global__ __launch_bounds__(256) void k_msg2_agg(
    const float* __restrict__ x2, const float* __restrict__ ea2,
    const int* __restrict__ ei2, const int* __restrict__ order,
    const float* __restrict__ Wa, const float* __restrict__ ba,
    const float* __restrict__ Wb, const float* __restrict__ bb,
    unsigned int* __restrict__ e_t, int E)
{
    __shared__ __align__(16) unsigned char sBuf[33792];  // In bf16[256][64] swz / H / msg f32[256][33]
    __shared__ __align__(16) unsigned char sWaB[8192];   // Wa^T bf16 [64][64] swz (K padded 48->64)
    __shared__ __align__(16) unsigned char sWbB[4096];   // Wb^T bf16 [32][64] swz
    __shared__ float sba[64], sbb[32];
    __shared__ int sdst[257];

    const int tid = threadIdx.x;
    // stage transposed weights (one-time, L2-resident reads)
    for (int i = tid; i < 64 * 64; i += 256) {
        int n = i >> 6, k = i & 63;
        float v = (k < 48) ? Wa[k * 64 + n] : 0.0f;
        *(unsigned short*)(sWaB + n * 128 + ((2 * k) ^ ((n & 7) << 4))) = f2bf(v);
    }
    for (int i = tid; i < 32 * 64; i += 256) {
        int n = i >> 6, k = i & 63;
        *(unsigned short*)(sWbB + n * 128 + ((2 * k) ^ ((n & 7) << 4))) = f2bf(Wb[k * 32 + n]);
    }
    if (tid < 64) sba[tid] = ba[tid];
    if (tid < 32) sbb[tid] = bb[tid];

    const int base = blockIdx.x * 256, p = base + tid;
    int e = 0, s = 0, d = -1;
    if (p < E) { e = order[p]; s = ei2[e]; d = ei2[E + e]; }
    sdst[tid] = d;
    int dprev = -1;
    if (tid == 0) {
        if (base > 0) { int ep = order[base - 1]; dprev = ei2[E + ep]; }
        int dn = -1;
        if (base + 256 < E) { int en = order[base + 256]; dn = ei2[E + en]; }
        sdst[256] = dn;
    }

    // stage this edge's input row: [x2[s](32), ea2[e](16), 0(16)] as bf16
    {
        uint4 ch[8];
        const float4* xs = (const float4*)(x2 + (size_t)s * 32);
        #pragma unroll
        for (int c = 0; c < 4; ++c) {
            float4 a = xs[2 * c], b = xs[2 * c + 1];
            ch[c].x = pack2(a.x, a.y); ch[c].y = pack2(a.z, a.w);
            ch[c].z = pack2(b.x, b.y); ch[c].w = pack2(b.z, b.w);
        }
        const float4* es = (const float4*)(ea2 + (size_t)e * 16);
        #pragma unroll
        for (int c = 0; c < 2; ++c) {
            float4 a = es[2 * c], b = es[2 * c + 1];
            ch[4 + c].x = pack2(a.x, a.y); ch[4 + c].y = pack2(a.z, a.w);
            ch[4 + c].z = pack2(b.x, b.y); ch[4 + c].w = pack2(b.z, b.w);
        }
        ch[6] = make_uint4(0, 0, 0, 0);
        ch[7] = make_uint4(0, 0, 0, 0);
        #pragma unroll
        for (int c = 0; c < 8; ++c)
            *(uint4*)(sBuf + swz(tid, c * 16)) = ch[c];
    }
    __syncthreads();

    const int lane = tid & 63, wv = tid >> 6;
    const int lr = lane & 15, lk = lane >> 4;
    const int band = wv * 64;  // each wave owns rows [band, band+64)

    // ---- layer A: H = relu(In @ Wa + ba), M=64/wave, N=64, K=64 ----
    f32x4 accA[4][4];
    #pragma unroll
    for (int n = 0; n < 4; ++n) {
        float bv = sba[n * 16 + lr];
        #pragma unroll
        for (int m = 0; m < 4; ++m) accA[m][n] = (f32x4){bv, bv, bv, bv};
    }
    #pragma unroll
    for (int ks = 0; ks < 2; ++ks) {
        const int kb = ks * 64 + lk * 16;
        bf16x8 af[4], bfr[4];
        #pragma unroll
        for (int m = 0; m < 4; ++m)
            af[m] = *(const bf16x8*)(sBuf + swz(band + m * 16 + lr, kb));
        #pragma unroll
        for (int n = 0; n < 4; ++n) {
            int rw = n * 16 + lr;
            bfr[n] = *(const bf16x8*)(sWaB + rw * 128 + (kb ^ ((rw & 7) << 4)));
        }
        #pragma unroll
        for (int m = 0; m < 4; ++m)
            #pragma unroll
            for (int n = 0; n < 4; ++n)
                accA[m][n] = __builtin_amdgcn_mfma_f32_16x16x32_bf16(af[m], bfr[n], accA[m][n], 0, 0, 0);
    }
    // relu -> bf16, write H over own band (C layout: col=lane&15, row=lk*4+r)
    #pragma unroll
    for (int m = 0; m < 4; ++m)
        #pragma unroll
        for (int n = 0; n < 4; ++n)
            #pragma unroll
            for (int r = 0; r < 4; ++r) {
                int grow = band + m * 16 + lk * 4 + r;
                int cb = 2 * (n * 16 + lr);
                *(unsigned short*)(sBuf + swz(grow, cb)) = f2bf(fmaxf(accA[m][n][r], 0.0f));
            }
    __syncthreads();

    // ---- layer B: Out = H @ Wb + bb, N=32 ----
    f32x4 accB[4][2];
    #pragma unroll
    for (int n = 0; n < 2; ++n) {
        float bv = sbb[n * 16 + lr];
        #pragma unroll
        for (int m = 0; m < 4; ++m) accB[m][n] = (f32x4){bv, bv, bv, bv};
    }
    #pragma unroll
    for (int ks = 0; ks < 2; ++ks) {
        const int kb = ks * 64 + lk * 16;
        bf16x8 af[4], bfr[2];
        #pragma unroll
        for (int m = 0; m < 4; ++m)
            af[m] = *(const bf16x8*)(sBuf + swz(band + m * 16 + lr, kb));
        #pragma unroll
        for (int n = 0; n < 2; ++n) {
            int rw = n * 16 + lr;
            bfr[n] = *(const bf16x8*)(sWbB + rw * 128 + (kb ^ ((rw & 7) << 4)));
        }
        #pragma unroll
        for (int m = 0; m < 4; ++m)
            #pragma unroll
            for (int n = 0; n < 2; ++n)
                accB[m][n] = __builtin_amdgcn_mfma_f32_16x16x32_bf16(af[m], bfr[n], accB[m][n], 0, 0, 0);
    }
    __syncthreads();  // everyone done reading H before msg overwrites bands

    float* smsg = (float*)sBuf;  // [256][33] f32
    #pragma unroll
    for (int m = 0; m < 4; ++m)
        #pragma unroll
        for (int n = 0; n < 2; ++n)
            #pragma unroll
            for (int r = 0; r < 4; ++r)
                smsg[(band + m * 16 + lk * 4 + r) * 33 + n * 16 + lr] = accB[m][n][r];
    __syncthreads();

    // ---- segmented reduce (identical to verified round-1 epilogue) ----
    const bool leader = (p < E) && (tid == 0 || sdst[tid - 1] != d);
    if (leader) {
        int qend = tid;
        while (qend + 1 < 256 && sdst[qend + 1] == d) ++qend;
        float acc[32];
        #pragma unroll
        for (int c = 0; c < 32; ++c) acc[c] = smsg[tid * 33 + c];
        for (int q = tid + 1; q <= qend; ++q) {
            #pragma unroll
            for (int c = 0; c < 32; ++c) acc[c] += smsg[q * 33 + c];
        }
        const bool gs = (tid > 0) || (base == 0) || (dprev != d);
        const bool ge = (qend < 255) || (sdst[256] != d);
        unsigned int* row = e_t + (size_t)d * 16;
        if (gs && ge) {
            #pragma unroll
            for (int q4 = 0; q4 < 4; ++q4) {
                uint4 o;
                o.x = pack2(acc[8 * q4 + 0], acc[8 * q4 + 1]);
                o.y = pack2(acc[8 * q4 + 2], acc[8 * q4 + 3]);
                o.z = pack2(acc[8 * q4 + 4], acc[8 * q4 + 5]);
                o.w = pack2(acc[8 * q4 + 6], acc[8 * q4 + 7]);
                ((uint4*)row)[q4] = o;
            }
        } else {
            for (int c = 0; c < 16; ++c) {
                unsigned int* addr = row + c;
                unsigned int old = *addr;
                while (true) {
                    float lo = bf2f(old & 0xffffu) + acc[2 * c];
                    float hi = bf2f(old >> 16) + acc[2 * c + 1];
                    unsigned int nv = pack2(lo, hi);
                    unsigned int prev = atomicCAS(addr, old, nv);
                    if (prev == old) break;
                    old = prev;
                }
            }
        }
    }
}

// ---------------- stage 2: MFMA MLP1 + segmented reduce -> h (f32) --------

__global__ __launch_bounds__(256) void k_msg1_agg(
    const float* __restrict__ x1, const unsigned int* __restrict__ e_t,
    const int* __restrict__ ei1, const int* __restrict__ order,
    const float* __restrict__ Wa, const float* __restrict__ ba,
    const float* __restrict__ Wb, const float* __restrict__ bb,
    float* __restrict__ h, int E)
{
    __shared__ __align__(16) unsigned char sBuf[33792];
    __shared__ __align__(16) unsigned char sWaB[8192];   // Wa^T bf16 [64][64] swz
    __shared__ __align__(16) unsigned char sWbB[4096];   // Wb^T bf16 [32][64] swz
    __shared__ float sba[64], sbb[32];
    __shared__ int sdst[257];

    const int tid = threadIdx.x;
    for (int i = tid; i < 64 * 64; i += 256) {
        int n = i >> 6, k = i & 63;
        *(unsigned short*)(sWaB + n * 128 + ((2 * k) ^ ((n & 7) << 4))) = f2bf(Wa[k * 64 + n]);
    }
    for (int i = tid; i < 32 * 64; i += 256) {
        int n = i >> 6, k = i & 63;
        *(unsigned short*)(sWbB + n * 128 + ((2 * k) ^ ((n & 7) << 4))) = f2bf(Wb[k * 32 + n]);
    }
    if (tid < 64) sba[tid] = ba[tid];
    if (tid < 32) sbb[tid] = bb[tid];

    const int base = blockIdx.x * 256, p = base + tid;
    int e = 0, s = 0, d = -1;
    if (p < E) { e = order[p]; s = ei1[e]; d = ei1[E + e]; }
    sdst[tid] = d;
    int dprev = -1;
    if (tid == 0) {
        if (base > 0) { int ep = order[base - 1]; dprev = ei1[E + ep]; }
        int dn = -1;
        if (base + 256 < E) { int en = order[base + 256]; dn = ei1[E + en]; }
        sdst[256] = dn;
    }

    // stage input row: [x1[s](32 f32->bf16), e_t[e](32 already bf16)]
    {
        uint4 ch[8];
        const float4* xs = (const float4*)(x1 + (size_t)s * 32);
        #pragma unroll
        for (int c = 0; c < 4; ++c) {
            float4 a = xs[2 * c], b = xs[2 * c + 1];
            ch[c].x = pack2(a.x, a.y); ch[c].y = pack2(a.z, a.w);
            ch[c].z = pack2(b.x, b.y); ch[c].w = pack2(b.z, b.w);
        }
        const uint4* er = (const uint4*)(e_t + (size_t)e * 16);
        #pragma unroll
        for (int c = 0; c < 4; ++c) ch[4 + c] = er[c];
        #pragma unroll
        for (int c = 0; c < 8; ++c)
            *(uint4*)(sBuf + swz(tid, c * 16)) = ch[c];
    }
    __syncthreads();

    const int lane = tid & 63, wv = tid >> 6;
    const int lr = lane & 15, lk = lane >> 4;
    const int band = wv * 64;

    f32x4 accA[4][4];
    #pragma unroll
    for (int n = 0; n < 4; ++n) {
        float bv = sba[n * 16 + lr];
        #pragma unroll
        for (int m = 0; m < 4; ++m) accA[m][n] = (f32x4){bv, bv, bv, bv};
    }
    #pragma unroll
    for (int ks = 0; ks < 2; ++ks) {
        const int kb = ks * 64 + lk * 16;
        bf16x8 af[4], bfr[4];
        #pragma unroll
        for (int m = 0; m < 4; ++m)
            af[m] = *(const bf16x8*)(sBuf + swz(band + m * 16 + lr, kb));
        #pragma unroll
        for (int n = 0; n < 4; ++n) {
            int rw = n * 16 + lr;
            bfr[n] = *(const bf16x8*)(sWaB + rw * 128 + (kb ^ ((rw & 7) << 4)));
        }
        #pragma unroll
        for (int m = 0; m < 4; ++m)
            #pragma unroll
            for (int n = 0; n < 4; ++n)
                accA[m][n] = __builtin_amdgcn_mfma_f32_16x16x32_bf16(af[m], bfr[n], accA[m][n], 0, 0, 0);
    }
    #pragma unroll
    for (int m = 0; m < 4; ++m)
        #pragma unroll
        for (int n = 0; n < 4; ++n)
            #pragma unroll
            for (int r = 0; r < 4; ++r) {
                int grow = band + m * 16 + lk * 4 + r;
                int cb = 2 * (n * 16 + lr);
                *(unsigned short*)(sBuf + swz(grow, cb)) = f2bf(fmaxf(accA[m][n][r], 0.0f));
            }
    __syncthreads();

    f32x4 accB[4][2];
    #pragma unroll
    for (int n = 0; n < 2; ++n) {
        float bv = sbb[n * 16 + lr];
        #pragma unroll
        for (int m = 0; m < 4; ++m) accB[m][n] = (f32x4){bv, bv, bv, bv};
    }
    #pragma unroll
    for (int ks = 0; ks < 2; ++ks) {
        const int kb = ks * 64 + lk * 16;
        bf16x8 af[4], bfr[2];
        #pragma unroll
        for (int m = 0; m < 4; ++m)
            af[m] = *(const bf16x8*)(sBuf + swz(band + m * 16 + lr, kb));
        #pragma unroll
        for (int n = 0; n < 2; ++n) {
            int rw = n * 16 + lr;
            bfr[n] = *(const bf16x8*)(sWbB + rw * 128 + (kb ^ ((rw & 7) << 4)));
        }
        #pragma unroll
        for (int m = 0; m < 4; ++m)
            #pragma unroll
            for (int n = 0; n < 2; ++n)
                accB[m][n] = __builtin_amdgcn_mfma_f32_16x16x32_bf16(af[m], bfr[n], accB[m][n], 0, 0, 0);
    }
    __syncthreads();

    float* smsg = (float*)sBuf;
    #pragma unroll
    for (int m = 0; m < 4; ++m)
        #pragma unroll
        for (int n = 0; n < 2; ++n)
            #pragma unroll
            for (int r = 0; r < 4; ++r)
                smsg[(band + m * 16 + lk * 4 + r) * 33 + n * 16 + lr] = accB[m][n][r];
    __syncthreads();

    const bool leader = (p < E) && (tid == 0 || sdst[tid - 1] != d);
    if (leader) {
        int qend = tid;
        while (qend + 1 < 256 && sdst[qend + 1] == d) ++qend;
        float acc[32];
        #pragma unroll
        for (int c = 0; c < 32; ++c) acc[c] = smsg[tid * 33 + c];
        for (int q = tid + 1; q <= qend; ++q) {
            #pragma unroll
            for (int c = 0; c < 32; ++c) acc[c] += smsg[q * 33 + c];
        }
        const bool gs = (tid > 0) || (base == 0) || (dprev != d);
        const bool ge = (qend < 255) || (sdst[256] != d);
        float* row = h + (size_t)d * 32;
        if (gs && ge) {
            #pragma unroll
            for (int q8 = 0; q8 < 8; ++q8)
                ((float4*)row)[q8] = make_float4(acc[4 * q8], acc[4 * q8 + 1],
                                                 acc[4 * q8 + 2], acc[4 * q8 + 3]);
        } else {
            for (int c = 0; c < 32; ++c) atomicAdd(row + c, acc[c]);
        }
    }
}

// ---------------- stage 3: pool per graph (batch is sorted) ----------------

__device__ __forceinline__ int lower_bound_i(const int* a, int n, int key) {
    int lo = 0, hi = n;
    while (lo < hi) {
        int mid = (lo + hi) >> 1;
        if (a[mid] < key) lo = mid + 1; else hi = mid;
    }
    return lo;
}

__global__ __launch_bounds__(256) void k_pool(const float* __restrict__ h,
                                              const int* __restrict__ batch,
                                              float* __restrict__ out, int N1) {
    const int g = blockIdx.x;
    const int lo = lower_bound_i(batch, N1, g);
    const int hi = lower_bound_i(batch, N1, g + 1);
    const int tid = threadIdx.x;
    const int c = tid & 31, rg = tid >> 5;
    float acc = 0.0f;
    for (int n = lo + rg; n < hi; n += 8) acc += h[(size_t)n * 32 + c];
    __shared__ float red[256];
    red[tid] = acc;
    __syncthreads();
    for (int off = 128; off >= 32; off >>= 1) {
        if (tid < off) red[tid] += red[tid + off];
        __syncthreads();
    }
    if (tid < 32) out[g * 32 + tid] = red[tid] * 0.5f;
}

// ---------------------------------------------------------------------------

extern "C" void kernel_launch(void* const* d_in, const int* in_sizes, int n_in,
                              void* d_out, int out_size, void* d_ws, size_t ws_size,
                              hipStream_t stream) {
    const float* x1  = (const float*)d_in[0];
    const float* x2  = (const float*)d_in[1];
    const int*   ei1 = (const int*)d_in[2];
    const int*   ei2 = (const int*)d_in[3];
    const int*   xb  = (const int*)d_in[4];
    const float* ea2 = (const float*)d_in[5];
    const float* W2a = (const float*)d_in[6];
    const float* b2a = (const float*)d_in[7];
    const float* W2b = (const float*)d_in[8];
    const float* b2b = (const float*)d_in[9];
    const float* W1a = (const float*)d_in[10];
    const float* b1a = (const float*)d_in[11];
    const float* W1b = (const float*)d_in[12];
    const float* b1b = (const float*)d_in[13];

    const int N1 = in_sizes[0] / 32;   // 20000
    const int E1 = in_sizes[2] / 2;    // 640000
    const int E2 = in_sizes[3] / 2;    // 1280000
    const int N2 = in_sizes[1] / 32;   // 640000 (== E1)

    char* w = (char*)d_ws;
    unsigned int* e_t = (unsigned int*)w;            w += (size_t)N2 * 32 * 2;  // bf16 [N2,32]
    int* cursor2      = (int*)w;                     w += (size_t)N2 * 4;
    int* order2       = (int*)w;                     w += (size_t)E2 * 4;
    int* aux          = (int*)w;                     w += 512 * 4;
    float* h          = (float*)w;                   w += (size_t)N1 * 32 * 4;
    int* cursor1      = (int*)w;                     w += (size_t)N1 * 4;
    int* order1       = (int*)w;

    const int G2 = (N2 + SCAN_EPB - 1) / SCAN_EPB;  // 313
    const int G1 = (N1 + SCAN_EPB - 1) / SCAN_EPB;  // 10

    // ---- graph 2: counting sort by dst ----
    hipMemsetAsync(cursor2, 0, (size_t)N2 * 4, stream);
    hipMemsetAsync(e_t, 0, (size_t)N2 * 32 * 2, stream);
    k_hist<<<(E2 + 255) / 256, 256, 0, stream>>>(ei2 + E2, cursor2, E2);
    k_scan_partial<<<G2, 256, 0, stream>>>(cursor2, aux, N2);
    k_scan_aux<<<1, 512, 0, stream>>>(aux, G2);
    k_scan_add<<<G2, 256, 0, stream>>>(cursor2, aux, N2);
    k_scatter<<<(E2 + 255) / 256, 256, 0, stream>>>(ei2 + E2, cursor2, order2, E2);

    // ---- stage 1 ----
    k_msg2_agg<<<(E2 + 255) / 256, 256, 0, stream>>>(
        x2, ea2, ei2, order2, W2a, b2a, W2b, b2b, e_t, E2);

    // ---- graph 1: counting sort by dst ----
    hipMemsetAsync(cursor1, 0, (size_t)N1 * 4, stream);
    hipMemsetAsync(h, 0, (size_t)N1 * 32 * 4, stream);
    k_hist<<<(E1 + 255) / 256, 256, 0, stream>>>(ei1 + E1, cursor1, E1);
    k_scan_partial<<<G1, 256, 0, stream>>>(cursor1, aux, N1);
    k_scan_aux<<<1, 512, 0, stream>>>(aux, G1);
    k_scan_add<<<G1, 256, 0, stream>>>(cursor1, aux, N1);
    k_scatter<<<(E1 + 255) / 256, 256, 0, stream>>>(ei1 + E1, cursor1, order1, E1);

    // ---- stage 2 ----
    k_msg1_agg<<<(E1 + 255) / 256, 256, 0, stream>>>(
        x1, e_t, ei1, order1, W1a, b1a, W1b, b1b, h, E1);

    // ---- stage 3 ----
    k_pool<<<NUM_GRAPHS, 256, 0, stream>>>(h, xb, (float*)d_out, N1);
}